// Round 4
// baseline (27.931 us; speedup 1.0000x reference)
//
#include <hip/hip_runtime.h>

#define D 64
#define STR 72    // LDS row stride in bf16 elems
#define WAVES 4   // independent waves per block, one sequence each

typedef __attribute__((ext_vector_type(8))) short bf16x8;
typedef __attribute__((ext_vector_type(4))) float f32x4;
typedef __attribute__((ext_vector_type(4))) unsigned int u32x4;

static __device__ __forceinline__ unsigned short f2bf(float f) {
  unsigned u = __builtin_bit_cast(unsigned, f);
  u += 0x7fffu + ((u >> 16) & 1u);  // RNE
  return (unsigned short)(u >> 16);
}

// per-wave LDS ordering (slices are wave-private; DS pipe is in-order per wave;
// the memory clobber pins compiler ordering of ds_write -> ds_read)
#define LDSWAIT() asm volatile("s_waitcnt lgkmcnt(0)" ::: "memory")

// 4 independent waves per block (NO __syncthreads anywhere — different L per
// wave would deadlock a barrier; slices are private so none is needed).
// Wave w of block b handles seq b + gridDim.x*w: 1024 % 8 == 0 so all four
// waves of a block share the same L -> uniform block runtime.
__global__ __launch_bounds__(256, 4)
void seq_attn_kernel(const float* __restrict__ h,
                     const int* __restrict__ sse,  // int32 (JAX x64 disabled)
                     float* __restrict__ out) {
  __shared__ unsigned short HsAll[WAVES * 64 * STR];  // 36.9 KB -> 4 blocks/CU

  const int tid = threadIdx.x;
  const int w = tid >> 6;
  const int lane = tid & 63;
  unsigned short* Hs = HsAll + w * (64 * STR);  // this wave's private slice

  const int s = blockIdx.x + gridDim.x * w;
  const int start = sse[2 * s];
  const int L = sse[2 * s + 1] - start;
  const int nt = (L + 15) >> 4;  // live 16-row tiles
  const int g = lane >> 4;       // 0..3
  const int c16 = lane & 15;     // 0..15

  // ---- stage H fp32->bf16: all loads issued up front (one latency) ----
  {
    const float* src = h + (size_t)start * D;
    const int c4 = c16 * 4;
    float4 va[8], vb[8];
    #pragma unroll
    for (int it = 0; it < 8; ++it) {
      const int r = it * 4 + g;
      const int rc = (r < L) ? r : 0;  // clamp: safe, masked at write
      va[it] = *(const float4*)(src + rc * D + c4);
    }
    const bool hi = (L > 32);  // wave-uniform: skip dead upper-half loads
    #pragma unroll
    for (int it = 0; it < 8; ++it) {
      const int r = 32 + it * 4 + g;
      const int rc = (r < L) ? r : 0;
      vb[it] = hi ? *(const float4*)(src + rc * D + c4) : make_float4(0.f, 0.f, 0.f, 0.f);
    }
    #pragma unroll
    for (int it = 0; it < 8; ++it) {
      const int r = it * 4 + g;
      const bool ok = (r < L);
      ushort4 wv;
      wv.x = ok ? f2bf(va[it].x) : (unsigned short)0;
      wv.y = ok ? f2bf(va[it].y) : (unsigned short)0;
      wv.z = ok ? f2bf(va[it].z) : (unsigned short)0;
      wv.w = ok ? f2bf(va[it].w) : (unsigned short)0;
      *(ushort4*)&Hs[r * STR + c4] = wv;  // rows >= L zeroed (pad keys -> 0 in PV)
    }
    #pragma unroll
    for (int it = 0; it < 8; ++it) {
      const int r = 32 + it * 4 + g;
      const bool ok = (r < L);
      ushort4 wv;
      wv.x = ok ? f2bf(vb[it].x) : (unsigned short)0;
      wv.y = ok ? f2bf(vb[it].y) : (unsigned short)0;
      wv.z = ok ? f2bf(vb[it].z) : (unsigned short)0;
      wv.w = ok ? f2bf(vb[it].w) : (unsigned short)0;
      *(ushort4*)&Hs[r * STR + c4] = wv;
    }
  }
  LDSWAIT();  // ds_writes drained before fragment reads (wave-private order)

  // ---- hf: A-layout fragments of H (both operands of S = H H^T by symmetry) ----
  bf16x8 hf[4][2];
  #pragma unroll
  for (int t = 0; t < 4; ++t)
    #pragma unroll
    for (int kb = 0; kb < 2; ++kb)
      hf[t][kb] = *(const bf16x8*)&Hs[(t * 16 + c16) * STR + kb * 32 + g * 8];

  // ---- vf: B-layout fragments for PV, preloaded BEFORE P overwrites Hs ----
  bf16x8 vf[4][2];
  #pragma unroll
  for (int t = 0; t < 4; ++t)
    #pragma unroll
    for (int kb = 0; kb < 2; ++kb) {
      u32x4 wv;
      #pragma unroll
      for (int dd = 0; dd < 4; ++dd) {
        const int k0 = kb * 32 + g * 8 + 2 * dd;
        const unsigned lo = Hs[k0 * STR + t * 16 + c16];
        const unsigned hi2 = Hs[(k0 + 1) * STR + t * 16 + c16];
        wv[dd] = lo | (hi2 << 16);
      }
      vf[t][kb] = __builtin_bit_cast(bf16x8, wv);
    }

  // ---- per 16-row tile: QK^T -> softmax -> P restage -> PV -> store ----
  #pragma unroll
  for (int ti = 0; ti < 4; ++ti) {
    if (ti >= nt) continue;  // wave-uniform

    f32x4 acc[4];
    #pragma unroll
    for (int tj = 0; tj < 4; ++tj) {
      f32x4 z = {0.f, 0.f, 0.f, 0.f};
      acc[tj] = z;
    }
    #pragma unroll
    for (int tj = 0; tj < 4; ++tj)
      #pragma unroll
      for (int kb = 0; kb < 2; ++kb)
        acc[tj] = __builtin_amdgcn_mfma_f32_16x16x32_bf16(
            hf[ti][kb], hf[tj][kb], acc[tj], 0, 0, 0);

    // softmax over key index. C layout: row = 16*ti + 4*g + r, col = 16*tj + c16.
    float inv[4];
    #pragma unroll
    for (int r = 0; r < 4; ++r) {
      float mx = -1e30f;
      #pragma unroll
      for (int tj = 0; tj < 4; ++tj) {
        const float sv = (tj * 16 + c16 < L) ? acc[tj][r] : -1e30f;
        acc[tj][r] = sv;
        mx = fmaxf(mx, sv);
      }
      #pragma unroll
      for (int off = 1; off < 16; off <<= 1)
        mx = fmaxf(mx, __shfl_xor(mx, off, 64));
      float sum = 0.f;
      #pragma unroll
      for (int tj = 0; tj < 4; ++tj) {
        const float p = __expf(acc[tj][r] - mx);
        acc[tj][r] = p;
        sum += p;
      }
      #pragma unroll
      for (int off = 1; off < 16; off <<= 1)
        sum += __shfl_xor(sum, off, 64);
      inv[r] = 1.0f / sum;  // normalization deferred to epilogue
    }

    // P tile (bf16) into Hs rows [16*ti, 16*ti+16) — hf/vf already in registers
    #pragma unroll
    for (int tj = 0; tj < 4; ++tj)
      #pragma unroll
      for (int r = 0; r < 4; ++r)
        Hs[(ti * 16 + g * 4 + r) * STR + tj * 16 + c16] = f2bf(acc[tj][r]);

    LDSWAIT();  // order ds_write(P) -> ds_read(pf) within the wave

    bf16x8 pf[2];
    #pragma unroll
    for (int kb = 0; kb < 2; ++kb)
      pf[kb] = *(const bf16x8*)&Hs[(ti * 16 + c16) * STR + kb * 32 + g * 8];

    f32x4 o[4];
    #pragma unroll
    for (int tjd = 0; tjd < 4; ++tjd) {
      f32x4 z = {0.f, 0.f, 0.f, 0.f};
      o[tjd] = z;
    }
    #pragma unroll
    for (int tjd = 0; tjd < 4; ++tjd)
      #pragma unroll
      for (int kb = 0; kb < 2; ++kb)
        o[tjd] = __builtin_amdgcn_mfma_f32_16x16x32_bf16(
            pf[kb], vf[tjd][kb], o[tjd], 0, 0, 0);

    #pragma unroll
    for (int r = 0; r < 4; ++r) {
      const int row = ti * 16 + g * 4 + r;
      if (row < L) {
        float* dst = out + (size_t)(start + row) * D;
        const float sc = inv[r];
        #pragma unroll
        for (int tjd = 0; tjd < 4; ++tjd)
          dst[tjd * 16 + c16] = o[tjd][r] * sc;
      }
    }
  }
}

extern "C" void kernel_launch(void* const* d_in, const int* in_sizes, int n_in,
                              void* d_out, int out_size, void* d_ws, size_t ws_size,
                              hipStream_t stream) {
  const float* h = (const float*)d_in[0];
  const int* sse = (const int*)d_in[1];
  float* out = (float*)d_out;
  const int nseq = in_sizes[1] / 2;       // 4096
  const int nblk = nseq / WAVES;          // 1024 workgroups of 4 waves
  seq_attn_kernel<<<nblk, 64 * WAVES, 0, stream>>>(h, sse, out);
}